// Round 11
// baseline (28.176 us; speedup 1.0000x reference)
//
#include <hip/hip_runtime.h>
#include <hip/hip_bf16.h>

// ---- problem constants ----
#define NEXP    32
#define KDIM    512
#define CDIM    1024
#define PAIRS   512
#define HALF_C  512
#define ALPHA   1.702f
#define LIMIT   7.0f

typedef __attribute__((ext_vector_type(8))) short short8;   // bf16x8 frag
typedef __attribute__((ext_vector_type(4))) float f32x4;

__device__ __forceinline__ unsigned pk2(float a, float b) {
    union { __hip_bfloat16 h; unsigned short u; } ca, cb;
    ca.h = __float2bfloat16(a);
    cb.h = __float2bfloat16(b);
    return (unsigned)ca.u | ((unsigned)cb.u << 16);
}

__device__ __forceinline__ short8 cvt8(float4 lo, float4 hi) {
    union { unsigned u[4]; short8 s; } r;
    r.u[0] = pk2(lo.x, lo.y);
    r.u[1] = pk2(lo.z, lo.w);
    r.u[2] = pk2(hi.x, hi.y);
    r.u[3] = pk2(hi.z, hi.w);
    return r.s;
}

__device__ __forceinline__ float glu_act(float g, float l) {
    g = fminf(g, LIMIT);
    l = fminf(fmaxf(l, -LIMIT), LIMIT);
    const float sg = 1.0f / (1.0f + __expf(-ALPHA * g));
    return (g * sg) * (l + 1.0f);
}

#define LDF4(p, off) (*(const float4*)((p) + (off)))

// =====================================================================
// Single fused kernel, BARRIER-FREE until the k-combine.
// Block = (16-ch chunk, expert); 4 waves = 4 K-quarters (k-split-4).
// Per wave (all wave-local, no __syncthreads before MFMA):
//   0. idx[512] loads (oldest on vmcnt FIFO)
//   1. W quarter (16ch x 128k fp32 = 8 KB) -> LDS via global_load_lds,
//      frag-linear; stays in flight under the whole prologue
//   2. ballot bucket -> wave-private token list (lgkmcnt only)
//   3. x quarter (32tok x 128k) -> bf16 frag-linear wave-private LDS
//   4. vmcnt(0) fence (W+x landed) -> 4 MFMA steps, LDS-only, 8 MFMAs
//   5. k-combine across waves (the only 2 barriers) + GLU epilogue
// Grid 64x32 = 2048 blocks @ 2 blocks/CU -> 8 pipelined generations:
// later blocks' prologues overlap earlier blocks' W streams.
// =====================================================================
__global__ __launch_bounds__(256, 2) void moe_mlp1_kernel(
    const float* __restrict__ x,      // [128, 512]
    const int* __restrict__ idx,      // [128, 4]
    const float* __restrict__ w,      // [32, 1024, 512]
    const float* __restrict__ bias,   // [32, 1024]
    float* __restrict__ out)          // [512, 512] fp32
{
    __shared__ __align__(16) float wlds[4][2048];   // 32 KB W (fp32, frag-linear)
    __shared__ __align__(16) char  xlds[4][8192];   // 32 KB x (bf16, frag-linear)
    __shared__ unsigned short wls[4][PAIRS];        // 4 KB wave-private lists
    __shared__ __align__(16) float red[3][64][8];   // 6 KB k-combine

    const int e     = blockIdx.y;
    const int cBase = blockIdx.x * 16;
    const int tid   = threadIdx.x;
    const int wv    = tid >> 6;        // wave id = K-quarter
    const int lane  = tid & 63;
    const int kg    = lane >> 4;       // k-group within an MFMA step
    const int c16   = lane & 15;
    const int tA    = lane & 15;

    // ---- 0. idx loads FIRST (older than W on the in-order vmcnt FIFO,
    //         so the ballot's wait leaves the W stream in flight) ----
    int iv[8];
    #pragma unroll
    for (int c = 0; c < 8; ++c) iv[c] = idx[c * 64 + lane];

    // ---- 1. W quarter -> LDS, frag-linear fp32, 8 global_load_lds ----
    // quad (s in 0..3, q in 0..7) at byte (s*8+q)*256 + c*16 holds
    // W[cBase+c][wv*128 + s*32 + q*4 .. +4].  Call j: s=j>>1, q=(j&1)*4+kg.
    const float* wbase = w + ((size_t)(e * CDIM + cBase + c16)) * KDIM + wv * 128;
    #pragma unroll
    for (int j = 0; j < 8; ++j) {
        const int s = j >> 1;
        const int q = (j & 1) * 4 + kg;
        const float* src = wbase + s * 32 + q * 4;
        __builtin_amdgcn_global_load_lds(
            (const __attribute__((address_space(1))) void*)src,
            (__attribute__((address_space(3))) void*)&wlds[wv][j * 256],
            16, 0, 0);
    }

    // ---- 2. ballot bucket (wave-local, zero barriers) ----
    const unsigned long long lt = (1ull << lane) - 1;
    int T = 0;
    #pragma unroll
    for (int c = 0; c < 8; ++c) {
        const bool hit = (iv[c] == e);
        const unsigned long long m = __ballot(hit);
        if (hit) wls[wv][T + (int)__popcll(m & lt)] = (unsigned short)(c * 64 + lane);
        T += (int)__popcll(m);
    }
    if (T == 0) {   // ~never; drain gll before workgroup teardown
        asm volatile("s_waitcnt vmcnt(0)" ::: "memory");
        return;
    }

    const float4 bv = *(const float4*)(bias + (size_t)e * CDIM + cBase + kg * 4);
    const int cb = cBase + kg * 4;     // epilogue channels cb..cb+3

    for (int tb = 0; tb < T; tb += 32) {
        const int nT = min(32, T - tb);

        // ---- 3. x quarter stage (wave-local): unit = (tok, step) ----
        // lane covers units u = lane, lane+64: t = lane&31, s = lane>>5 (+2).
        #pragma unroll
        for (int r = 0; r < 2; ++r) {
            const int t = lane & 31;
            const int s = (lane >> 5) + r * 2;
            if (t < nT) {
                const int pr = (int)wls[wv][tb + t];
                const float* xr = x + (size_t)(pr >> 2) * KDIM + wv * 128 + s * 32;
                const float4 f0 = LDF4(xr, 0),  f1 = LDF4(xr, 4);
                const float4 f2 = LDF4(xr, 8),  f3 = LDF4(xr, 12);
                const float4 f4 = LDF4(xr, 16), f5 = LDF4(xr, 20);
                const float4 f6 = LDF4(xr, 24), f7 = LDF4(xr, 28);
                char* db = &xlds[wv][(s * 2 + (t >> 4)) * 1024 + (t & 15) * 16];
                *(short8*)(db + 0)   = cvt8(f0, f1);
                *(short8*)(db + 256) = cvt8(f2, f3);
                *(short8*)(db + 512) = cvt8(f4, f5);
                *(short8*)(db + 768) = cvt8(f6, f7);
            }
        }

        const int pr0 = (tA < nT)      ? (int)wls[wv][tb + tA]      : -1;
        const int pr1 = (tA + 16 < nT) ? (int)wls[wv][tb + tA + 16] : -1;

        // gll (W) completion fence; compiler handles x ds_write->ds_read
        asm volatile("s_waitcnt vmcnt(0)" ::: "memory");
        __builtin_amdgcn_sched_barrier(0);

        // ---- 4. K-loop: 4 steps, LDS-only, no barriers ----
        f32x4 acc0 = {0.f, 0.f, 0.f, 0.f};
        f32x4 acc1 = {0.f, 0.f, 0.f, 0.f};
        const char* xw = (const char*)&xlds[wv][0] + lane * 16;
        const char* ww = (const char*)&wlds[wv][0] + kg * 512 + c16 * 16;
        #pragma unroll
        for (int s = 0; s < 4; ++s) {
            const float4 a0 = *(const float4*)(ww + s * 2048);
            const float4 a1 = *(const float4*)(ww + s * 2048 + 256);
            const short8 A  = cvt8(a0, a1);
            const short8 B0 = *(const short8*)(xw + s * 2048);
            const short8 B1 = *(const short8*)(xw + s * 2048 + 1024);
            acc0 = __builtin_amdgcn_mfma_f32_16x16x32_bf16(A, B0, acc0, 0, 0, 0);
            acc1 = __builtin_amdgcn_mfma_f32_16x16x32_bf16(A, B1, acc1, 0, 0, 0);
        }

        // ---- 5. k-split-4 combine (the only barriers) + epilogue ----
        __syncthreads();
        if (wv != 0) {
            float* rp = &red[wv - 1][lane][0];
            *(f32x4*)rp       = acc0;
            *(f32x4*)(rp + 4) = acc1;
        }
        __syncthreads();
        if (wv == 0) {
            #pragma unroll
            for (int rr = 0; rr < 3; ++rr) {
                const float* rp = &red[rr][lane][0];
                #pragma unroll
                for (int i = 0; i < 4; ++i) {
                    acc0[i] += rp[i];
                    acc1[i] += rp[4 + i];
                }
            }
            if (pr0 >= 0) {
                float2 o;
                o.x = glu_act(acc0[0] + bv.x, acc0[1] + bv.y);
                o.y = glu_act(acc0[2] + bv.z, acc0[3] + bv.w);
                *(float2*)&out[(size_t)pr0 * HALF_C + (cb >> 1)] = o;
            }
            if (pr1 >= 0) {
                float2 o;
                o.x = glu_act(acc1[0] + bv.x, acc1[1] + bv.y);
                o.y = glu_act(acc1[2] + bv.z, acc1[3] + bv.w);
                *(float2*)&out[(size_t)pr1 * HALF_C + (cb >> 1)] = o;
            }
        }
    }
}

extern "C" void kernel_launch(void* const* d_in, const int* in_sizes, int n_in,
                              void* d_out, int out_size, void* d_ws, size_t ws_size,
                              hipStream_t stream) {
    const float* x    = (const float*)d_in[0];
    const int*   idx  = (const int*)d_in[1];
    const float* w    = (const float*)d_in[2];
    const float* bias = (const float*)d_in[3];
    float* out = (float*)d_out;

    dim3 grid(CDIM / 16, NEXP);   // (64, 32) = 2048 blocks, 2/CU resident
    moe_mlp1_kernel<<<grid, 256, 0, stream>>>(x, idx, w, bias, out);
}

// Round 12
// 26.069 us; speedup vs baseline: 1.0808x; 1.0808x over previous
//
#include <hip/hip_runtime.h>
#include <hip/hip_bf16.h>

// ---- problem constants ----
#define NEXP    32
#define KDIM    512
#define CDIM    1024
#define PAIRS   512
#define HALF_C  512
#define ALPHA   1.702f
#define LIMIT   7.0f

typedef __attribute__((ext_vector_type(8))) short short8;   // bf16x8 frag
typedef __attribute__((ext_vector_type(4))) float f32x4;

__device__ __forceinline__ unsigned pk2(float a, float b) {
    union { __hip_bfloat16 h; unsigned short u; } ca, cb;
    ca.h = __float2bfloat16(a);
    cb.h = __float2bfloat16(b);
    return (unsigned)ca.u | ((unsigned)cb.u << 16);
}

__device__ __forceinline__ short8 cvt8(float4 lo, float4 hi) {
    union { unsigned u[4]; short8 s; } r;
    r.u[0] = pk2(lo.x, lo.y);
    r.u[1] = pk2(lo.z, lo.w);
    r.u[2] = pk2(hi.x, hi.y);
    r.u[3] = pk2(hi.z, hi.w);
    return r.s;
}

__device__ __forceinline__ float glu_act(float g, float l) {
    g = fminf(g, LIMIT);
    l = fminf(fmaxf(l, -LIMIT), LIMIT);
    const float sg = 1.0f / (1.0f + __expf(-ALPHA * g));
    return (g * sg) * (l + 1.0f);
}

#define LDF4(p, off) (*(const float4*)((p) + (off)))

// =====================================================================
// Single fused kernel, NO barrier between entry and MFMA.
// Block = (16-ch chunk, expert); 4 waves = 4 K-quarters (k-split-4).
// Per-wave timeline (everything wave-local until the k-combine):
//   0. 8 idx loads (issued first -> retire first, in-order vmcnt)
//   1. 8 W float4 loads -> 32 VGPRs (16ch x 128k quarter) -- the HBM
//      stream is in flight from t~0 and nothing drains it early
//   2. ballot bucket (waits only for idx: vmcnt(8)-style) -> wave list
//   3. x quarter (32tok x 128k) staged to wave-PRIVATE LDS frags
//      (x data retires after W -> cvt+MFMA form the natural tail)
//   4. 4 MFMA steps (8 MFMAs max), LDS conflict-free b128 reads
//   5. k-combine: waves 1-3 write acc into their own (dead) x region,
//      ONE barrier, wave 0 sums + GLU epilogue. 2 barriers/chunk total.
// Grid (64,32) = 2048 blocks @ 4/CU (36 KB LDS) -> 2 generations:
// gen-2 prologues overlap gen-1 W streams; HBM duty ~continuous.
// =====================================================================
__global__ __launch_bounds__(256, 4) void moe_mlp1_kernel(
    const float* __restrict__ x,      // [128, 512]
    const int* __restrict__ idx,      // [128, 4]
    const float* __restrict__ w,      // [32, 1024, 512]
    const float* __restrict__ bias,   // [32, 1024]
    float* __restrict__ out)          // [512, 512] fp32
{
    __shared__ __align__(16) char xlds[4][8192];   // 32 KB wave-private frags
    __shared__ unsigned short    wls[4][PAIRS];    // 4 KB wave-private lists

    const int e     = blockIdx.y;
    const int cBase = blockIdx.x * 16;
    const int tid   = threadIdx.x;
    const int wv    = tid >> 6;        // wave id = K-quarter
    const int lane  = tid & 63;
    const int kg    = lane >> 4;       // k-group within an MFMA step
    const int c16   = lane & 15;
    const int tA    = lane & 15;

    // ---- 0. idx loads (oldest on the vmcnt FIFO) ----
    int iv[8];
    #pragma unroll
    for (int c = 0; c < 8; ++c) iv[c] = idx[c * 64 + lane];

    // ---- 1. W quarter -> VGPR ring (32 VGPRs), issued at entry ----
    const float* wp = w + ((size_t)(e * CDIM + cBase + c16)) * KDIM
                        + wv * 128 + kg * 8;
    float4 w0[4], w1[4];
    #pragma unroll
    for (int s = 0; s < 4; ++s) {
        w0[s] = LDF4(wp, s * 32);
        w1[s] = LDF4(wp, s * 32 + 4);
    }

    // bias for epilogue (tiny; rides the stream)
    const float4 bv = *(const float4*)(bias + (size_t)e * CDIM + cBase + kg * 4);
    const int cb = cBase + kg * 4;

    // ---- 2. ballot bucket (wave-local; waits only for idx) ----
    const unsigned long long lt = (1ull << lane) - 1;
    int T = 0;
    #pragma unroll
    for (int c = 0; c < 8; ++c) {
        const bool hit = (iv[c] == e);
        const unsigned long long m = __ballot(hit);
        if (hit) wls[wv][T + (int)__popcll(m & lt)] = (unsigned short)(c * 64 + lane);
        T += (int)__popcll(m);
    }

    for (int tb = 0; tb < T; tb += 32) {
        if (tb) __syncthreads();               // red-overlay reuse guard
        const int nT = min(32, T - tb);

        // ---- 3. x quarter -> wave-private LDS frags (bf16) ----
        // unit u = lane + r*64: tok t = u&31, seg s = u>>5 (32 k's each)
        #pragma unroll
        for (int r = 0; r < 2; ++r) {
            const int u = lane + r * 64;
            const int t = u & 31;
            const int s = u >> 5;
            if (t < nT) {
                const int pr = (int)wls[wv][tb + t];
                const float* xr = x + (size_t)(pr >> 2) * KDIM + wv * 128 + s * 32;
                const float4 f0 = LDF4(xr, 0),  f1 = LDF4(xr, 4);
                const float4 f2 = LDF4(xr, 8),  f3 = LDF4(xr, 12);
                const float4 f4 = LDF4(xr, 16), f5 = LDF4(xr, 20);
                const float4 f6 = LDF4(xr, 24), f7 = LDF4(xr, 28);
                char* db = &xlds[wv][(s * 2 + (t >> 4)) * 1024 + (t & 15) * 16];
                *(short8*)(db + 0)   = cvt8(f0, f1);
                *(short8*)(db + 256) = cvt8(f2, f3);
                *(short8*)(db + 512) = cvt8(f4, f5);
                *(short8*)(db + 768) = cvt8(f6, f7);
            }
        }

        const int pr0 = (tA < nT)      ? (int)wls[wv][tb + tA]      : -1;
        const int pr1 = (tA + 16 < nT) ? (int)wls[wv][tb + tA + 16] : -1;
        const bool h2 = nT > 16;               // wave-uniform

        // ---- 4. MFMA: 4 steps, LDS-only, no barrier ----
        f32x4 acc0 = {0.f, 0.f, 0.f, 0.f};
        f32x4 acc1 = {0.f, 0.f, 0.f, 0.f};
        const char* xw = (const char*)&xlds[wv][0] + lane * 16;
        #pragma unroll
        for (int s = 0; s < 4; ++s) {
            const short8 A  = cvt8(w0[s], w1[s]);
            const short8 B0 = *(const short8*)(xw + s * 2048);
            acc0 = __builtin_amdgcn_mfma_f32_16x16x32_bf16(A, B0, acc0, 0, 0, 0);
            if (h2) {
                const short8 B1 = *(const short8*)(xw + s * 2048 + 1024);
                acc1 = __builtin_amdgcn_mfma_f32_16x16x32_bf16(A, B1, acc1, 0, 0, 0);
            }
        }

        // ---- 5. k-combine: red overlaid on each wave's dead x region ----
        if (wv != 0) {
            float* rp = (float*)&xlds[wv][lane * 32];
            *(f32x4*)rp       = acc0;
            *(f32x4*)(rp + 4) = acc1;
        }
        __syncthreads();
        if (wv == 0) {
            #pragma unroll
            for (int rr = 1; rr < 4; ++rr) {
                const float* rp = (const float*)&xlds[rr][lane * 32];
                #pragma unroll
                for (int i = 0; i < 4; ++i) {
                    acc0[i] += rp[i];
                    acc1[i] += rp[4 + i];
                }
            }
            if (pr0 >= 0) {
                float2 o;
                o.x = glu_act(acc0[0] + bv.x, acc0[1] + bv.y);
                o.y = glu_act(acc0[2] + bv.z, acc0[3] + bv.w);
                *(float2*)&out[(size_t)pr0 * HALF_C + (cb >> 1)] = o;
            }
            if (pr1 >= 0) {
                float2 o;
                o.x = glu_act(acc1[0] + bv.x, acc1[1] + bv.y);
                o.y = glu_act(acc1[2] + bv.z, acc1[3] + bv.w);
                *(float2*)&out[(size_t)pr1 * HALF_C + (cb >> 1)] = o;
            }
        }
    }
}

extern "C" void kernel_launch(void* const* d_in, const int* in_sizes, int n_in,
                              void* d_out, int out_size, void* d_ws, size_t ws_size,
                              hipStream_t stream) {
    const float* x    = (const float*)d_in[0];
    const int*   idx  = (const int*)d_in[1];
    const float* w    = (const float*)d_in[2];
    const float* bias = (const float*)d_in[3];
    float* out = (float*)d_out;

    dim3 grid(CDIM / 16, NEXP);   // (64, 32) = 2048 blocks, 4/CU, 2 gens
    moe_mlp1_kernel<<<grid, 256, 0, stream>>>(x, idx, w, bias, out);
}

// Round 13
// 21.360 us; speedup vs baseline: 1.3191x; 1.2205x over previous
//
#include <hip/hip_runtime.h>
#include <hip/hip_bf16.h>

// ---- problem constants ----
#define NEXP    32
#define KDIM    512
#define CDIM    1024
#define PAIRS   512
#define HALF_C  512
#define ALPHA   1.702f
#define LIMIT   7.0f

typedef __attribute__((ext_vector_type(8))) short short8;   // bf16x8 frag
typedef __attribute__((ext_vector_type(4))) float f32x4;

__device__ __forceinline__ unsigned pk2(float a, float b) {
    union { __hip_bfloat16 h; unsigned short u; } ca, cb;
    ca.h = __float2bfloat16(a);
    cb.h = __float2bfloat16(b);
    return (unsigned)ca.u | ((unsigned)cb.u << 16);
}

__device__ __forceinline__ short8 cvt8(float4 lo, float4 hi) {
    union { unsigned u[4]; short8 s; } r;
    r.u[0] = pk2(lo.x, lo.y);
    r.u[1] = pk2(lo.z, lo.w);
    r.u[2] = pk2(hi.x, hi.y);
    r.u[3] = pk2(hi.z, hi.w);
    return r.s;
}

__device__ __forceinline__ float glu_act(float g, float l) {
    g = fminf(g, LIMIT);
    l = fminf(fmaxf(l, -LIMIT), LIMIT);
    const float sg = 1.0f / (1.0f + __expf(-ALPHA * g));
    return (g * sg) * (l + 1.0f);
}

#define LDF4(p, off) (*(const float4*)((p) + (off)))

// =====================================================================
// Single fused kernel; NO barrier between entry and MFMA.
// Block = (32-ch chunk, expert), grid (32,32)=1024 = 4/CU, ONE
// generation. 4 waves = 4 K-quarters (k-split-4), wave-private:
//   0. 8 idx loads (oldest on the per-wave in-order vmcnt FIFO)
//   1. ballot bucket -> wave-private token list (waits only on idx)
//   2. W quarter 32ch x 128k -> 64 VGPRs (16 dwordx4): the block's
//      whole HBM stream is in flight ~immediately; nothing drains it
//   3. x quarter staged to wave-PRIVATE LDS frags (cvt naturally
//      starts when this wave's W has landed -- in-order retire)
//   4. 4 MFMA steps x up-to-4 MFMAs (2 ch-tiles x 2 tok-halves)
//   5. k-combine: waves 1-3 dump accs into their own dead x region
//      (b128, conflict-free), ONE barrier, wave 0 sums + GLU stores.
// Chip-wide: all 1024 blocks queue their W at t~0 -> HBM duty ~100%;
// per-wave tails (cvt+MFMA) overlap other waves' still-arriving W.
// =====================================================================
__global__ __launch_bounds__(256, 4) void moe_mlp1_kernel(
    const float* __restrict__ x,      // [128, 512]
    const int* __restrict__ idx,      // [128, 4]
    const float* __restrict__ w,      // [32, 1024, 512]
    const float* __restrict__ bias,   // [32, 1024]
    float* __restrict__ out)          // [512, 512] fp32
{
    __shared__ __align__(16) char xlds[4][8192];   // wave-private frags (32 KB)
    __shared__ unsigned short    wls[4][PAIRS];    // wave-private lists (4 KB)

    const int e     = blockIdx.y;
    const int cBase = blockIdx.x * 32;
    const int tid   = threadIdx.x;
    const int wv    = tid >> 6;        // wave id = K-quarter
    const int lane  = tid & 63;
    const int kg    = lane >> 4;       // k-group within an MFMA step
    const int c16   = lane & 15;
    const int tA    = lane & 15;

    // ---- 0. idx loads ----
    int iv[8];
    #pragma unroll
    for (int c = 0; c < 8; ++c) iv[c] = idx[c * 64 + lane];

    // ---- 1. ballot bucket (wave-local, no barrier) ----
    const unsigned long long lt = (1ull << lane) - 1;
    int T = 0;
    #pragma unroll
    for (int c = 0; c < 8; ++c) {
        const bool hit = (iv[c] == e);
        const unsigned long long m = __ballot(hit);
        if (hit) wls[wv][T + (int)__popcll(m & lt)] = (unsigned short)(c * 64 + lane);
        T += (int)__popcll(m);
    }
    if (T == 0) return;                // expert got no tokens: skip W entirely

    // ---- 2. W quarter -> 64 VGPRs (16 dwordx4), the HBM stream ----
    const float* wpA0 = w + (size_t)(e * CDIM + cBase + c16) * KDIM
                          + wv * 128 + kg * 8;
    const float* wpA1 = wpA0 + 16 * KDIM;
    float4 a0lo[4], a0hi[4], a1lo[4], a1hi[4];
    #pragma unroll
    for (int s = 0; s < 4; ++s) {
        a0lo[s] = LDF4(wpA0, s * 32);
        a0hi[s] = LDF4(wpA0, s * 32 + 4);
        a1lo[s] = LDF4(wpA1, s * 32);
        a1hi[s] = LDF4(wpA1, s * 32 + 4);
    }

    // bias (tiny; rides the stream)
    const float4 bv0 = *(const float4*)(bias + (size_t)e * CDIM + cBase + kg * 4);
    const float4 bv1 = *(const float4*)(bias + (size_t)e * CDIM + cBase + 16 + kg * 4);
    const int cb0 = cBase + kg * 4;
    const int cb1 = cBase + 16 + kg * 4;

    for (int tb = 0; tb < T; tb += 32) {
        if (tb) __syncthreads();               // region reuse guard (rare)
        const int nT = min(32, T - tb);
        const bool h2 = nT > 16;               // wave-uniform

        // ---- 3. x quarter -> wave-private LDS frags (bf16) ----
        // unit u = lane + r*64: tok t = u&31, seg s = u>>5 (32 k's each);
        // frag f = s*2 + (t>>4), kg-part g at g*256 + (t&15)*16.
        #pragma unroll
        for (int r = 0; r < 2; ++r) {
            const int u = lane + r * 64;
            const int t = u & 31;
            const int s = u >> 5;
            if (t < nT) {
                const int pr = (int)wls[wv][tb + t];
                const float* xr = x + (size_t)(pr >> 2) * KDIM + wv * 128 + s * 32;
                char* db = &xlds[wv][(s * 2 + (t >> 4)) * 1024 + (t & 15) * 16];
                #pragma unroll
                for (int g = 0; g < 4; ++g) {
                    const float4 f0 = LDF4(xr, g * 8);
                    const float4 f1 = LDF4(xr, g * 8 + 4);
                    *(short8*)(db + g * 256) = cvt8(f0, f1);
                }
            }
        }

        const int pr0 = (tA < nT)      ? (int)wls[wv][tb + tA]      : -1;
        const int pr1 = (tA + 16 < nT) ? (int)wls[wv][tb + tA + 16] : -1;

        // ---- 4. MFMA: 4 steps, LDS+VGPR only, no barrier ----
        f32x4 acc00 = {0.f, 0.f, 0.f, 0.f};   // ch-tile 0, tok 0-15
        f32x4 acc01 = {0.f, 0.f, 0.f, 0.f};   // ch-tile 0, tok 16-31
        f32x4 acc10 = {0.f, 0.f, 0.f, 0.f};   // ch-tile 1, tok 0-15
        f32x4 acc11 = {0.f, 0.f, 0.f, 0.f};   // ch-tile 1, tok 16-31
        const char* xw = (const char*)&xlds[wv][0] + lane * 16;
        #pragma unroll
        for (int s = 0; s < 4; ++s) {
            const short8 A0 = cvt8(a0lo[s], a0hi[s]);
            const short8 A1 = cvt8(a1lo[s], a1hi[s]);
            const short8 B0 = *(const short8*)(xw + s * 2048);
            acc00 = __builtin_amdgcn_mfma_f32_16x16x32_bf16(A0, B0, acc00, 0, 0, 0);
            acc10 = __builtin_amdgcn_mfma_f32_16x16x32_bf16(A1, B0, acc10, 0, 0, 0);
            if (h2) {
                const short8 B1 = *(const short8*)(xw + s * 2048 + 1024);
                acc01 = __builtin_amdgcn_mfma_f32_16x16x32_bf16(A0, B1, acc01, 0, 0, 0);
                acc11 = __builtin_amdgcn_mfma_f32_16x16x32_bf16(A1, B1, acc11, 0, 0, 0);
            }
        }

        // ---- 5. k-combine on dead x regions (b128, conflict-free) ----
        if (wv != 0) {
            char* rb = &xlds[wv][lane * 16];
            *(f32x4*)(rb + 0)    = acc00;
            *(f32x4*)(rb + 1024) = acc01;
            *(f32x4*)(rb + 2048) = acc10;
            *(f32x4*)(rb + 3072) = acc11;
        }
        __syncthreads();
        if (wv == 0) {
            #pragma unroll
            for (int rr = 1; rr < 4; ++rr) {
                const char* rb = &xlds[rr][lane * 16];
                acc00 = acc00 + *(const f32x4*)(rb + 0);
                acc01 = acc01 + *(const f32x4*)(rb + 1024);
                acc10 = acc10 + *(const f32x4*)(rb + 2048);
                acc11 = acc11 + *(const f32x4*)(rb + 3072);
            }
            if (pr0 >= 0) {
                float2 o;
                o.x = glu_act(acc00[0] + bv0.x, acc00[1] + bv0.y);
                o.y = glu_act(acc00[2] + bv0.z, acc00[3] + bv0.w);
                *(float2*)&out[(size_t)pr0 * HALF_C + (cb0 >> 1)] = o;
                o.x = glu_act(acc10[0] + bv1.x, acc10[1] + bv1.y);
                o.y = glu_act(acc10[2] + bv1.z, acc10[3] + bv1.w);
                *(float2*)&out[(size_t)pr0 * HALF_C + (cb1 >> 1)] = o;
            }
            if (pr1 >= 0) {
                float2 o;
                o.x = glu_act(acc01[0] + bv0.x, acc01[1] + bv0.y);
                o.y = glu_act(acc01[2] + bv0.z, acc01[3] + bv0.w);
                *(float2*)&out[(size_t)pr1 * HALF_C + (cb0 >> 1)] = o;
                o.x = glu_act(acc11[0] + bv1.x, acc11[1] + bv1.y);
                o.y = glu_act(acc11[2] + bv1.z, acc11[3] + bv1.w);
                *(float2*)&out[(size_t)pr1 * HALF_C + (cb1 >> 1)] = o;
            }
        }
    }
}

extern "C" void kernel_launch(void* const* d_in, const int* in_sizes, int n_in,
                              void* d_out, int out_size, void* d_ws, size_t ws_size,
                              hipStream_t stream) {
    const float* x    = (const float*)d_in[0];
    const int*   idx  = (const int*)d_in[1];
    const float* w    = (const float*)d_in[2];
    const float* bias = (const float*)d_in[3];
    float* out = (float*)d_out;

    dim3 grid(CDIM / 32, NEXP);   // (32, 32) = 1024 blocks = 4/CU, 1 generation
    moe_mlp1_kernel<<<grid, 256, 0, stream>>>(x, idx, w, bias, out);
}

// Round 14
// 20.363 us; speedup vs baseline: 1.3837x; 1.0489x over previous
//
#include <hip/hip_runtime.h>
#include <hip/hip_bf16.h>

// ---- problem constants ----
#define NEXP    32
#define KDIM    512
#define CDIM    1024
#define PAIRS   512
#define HALF_C  512
#define ALPHA   1.702f
#define LIMIT   7.0f

typedef __attribute__((ext_vector_type(8))) short short8;   // bf16x8 frag
typedef __attribute__((ext_vector_type(4))) float f32x4;

__device__ __forceinline__ unsigned pk2(float a, float b) {
    union { __hip_bfloat16 h; unsigned short u; } ca, cb;
    ca.h = __float2bfloat16(a);
    cb.h = __float2bfloat16(b);
    return (unsigned)ca.u | ((unsigned)cb.u << 16);
}

__device__ __forceinline__ short8 cvt8(float4 lo, float4 hi) {
    union { unsigned u[4]; short8 s; } r;
    r.u[0] = pk2(lo.x, lo.y);
    r.u[1] = pk2(lo.z, lo.w);
    r.u[2] = pk2(hi.x, hi.y);
    r.u[3] = pk2(hi.z, hi.w);
    return r.s;
}

__device__ __forceinline__ float glu_act(float g, float l) {
    g = fminf(g, LIMIT);
    l = fminf(fmaxf(l, -LIMIT), LIMIT);
    const float sg = 1.0f / (1.0f + __expf(-ALPHA * g));
    return (g * sg) * (l + 1.0f);
}

#define LDF4(p, off) (*(const float4*)((p) + (off)))

// =====================================================================
// Single fused kernel; NO barrier between entry and the k-combine.
// Block = (32-ch chunk, expert), grid (32,32) = 1024 = 4/CU exactly.
// 4 waves = 4 K-quarters (k-split-4), fully wave-private until combine.
//
// W issued in TWO 8-load batches (32 VGPRs live each, peak VGPR ~90):
//   0. idx loads (oldest on the in-order vmcnt FIFO)
//   1. W batch0 (MFMA steps 0-1) -- HBM stream live from t~0
//   2. ballot bucket (counted wait: only idx drains; W stays in flight)
//   3. x quarter -> wave-private LDS frags (overlaps W batch0 arrival)
//   4. W batch1 (steps 2-3) issued, flies under batch0's MFMAs
//   5. 4 MFMA steps x up-to-4 MFMAs, counted vmcnt waits only
//   6. k-combine on dead x regions: ONE barrier, wave 0 sums + GLU.
// =====================================================================
__global__ __launch_bounds__(256, 4) void moe_mlp1_kernel(
    const float* __restrict__ x,      // [128, 512]
    const int* __restrict__ idx,      // [128, 4]
    const float* __restrict__ w,      // [32, 1024, 512]
    const float* __restrict__ bias,   // [32, 1024]
    float* __restrict__ out)          // [512, 512] fp32
{
    __shared__ __align__(16) char xlds[4][8192];   // wave-private frags (32 KB)
    __shared__ unsigned short    wls[4][PAIRS];    // wave-private lists (4 KB)

    const int e     = blockIdx.y;
    const int cBase = blockIdx.x * 32;
    const int tid   = threadIdx.x;
    const int wv    = tid >> 6;        // wave id = K-quarter
    const int lane  = tid & 63;
    const int kg    = lane >> 4;       // k-group within an MFMA step
    const int c16   = lane & 15;
    const int tA    = lane & 15;

    // ---- 0. idx loads (oldest on FIFO) ----
    int iv[8];
    #pragma unroll
    for (int c = 0; c < 8; ++c) iv[c] = idx[c * 64 + lane];

    // ---- 1. W batch0: steps 0-1, 8 dwordx4 (32 VGPRs) ----
    const float* wpA0 = w + (size_t)(e * CDIM + cBase + c16) * KDIM
                          + wv * 128 + kg * 8;
    const float* wpA1 = wpA0 + 16 * KDIM;
    float4 b0a0lo[2], b0a0hi[2], b0a1lo[2], b0a1hi[2];
    #pragma unroll
    for (int s = 0; s < 2; ++s) {
        b0a0lo[s] = LDF4(wpA0, s * 32);
        b0a0hi[s] = LDF4(wpA0, s * 32 + 4);
        b0a1lo[s] = LDF4(wpA1, s * 32);
        b0a1hi[s] = LDF4(wpA1, s * 32 + 4);
    }

    // bias rides the stream
    const float4 bv0 = *(const float4*)(bias + (size_t)e * CDIM + cBase + kg * 4);
    const float4 bv1 = *(const float4*)(bias + (size_t)e * CDIM + cBase + 16 + kg * 4);
    const int cb0 = cBase + kg * 4;
    const int cb1 = cBase + 16 + kg * 4;

    // ---- 2. ballot bucket (wave-local; counted wait on idx only) ----
    const unsigned long long lt = (1ull << lane) - 1;
    int T = 0;
    #pragma unroll
    for (int c = 0; c < 8; ++c) {
        const bool hit = (iv[c] == e);
        const unsigned long long m = __ballot(hit);
        if (hit) wls[wv][T + (int)__popcll(m & lt)] = (unsigned short)(c * 64 + lane);
        T += (int)__popcll(m);
    }

    for (int tb = 0; tb < T; tb += 32) {
        if (tb) __syncthreads();               // region reuse guard (rare)
        const int nT = min(32, T - tb);
        const bool h2 = nT > 16;               // wave-uniform

        // ---- 3. x quarter -> wave-private LDS frags (bf16) ----
        #pragma unroll
        for (int r = 0; r < 2; ++r) {
            const int u = lane + r * 64;
            const int t = u & 31;
            const int s = u >> 5;
            if (t < nT) {
                const int pr = (int)wls[wv][tb + t];
                const float* xr = x + (size_t)(pr >> 2) * KDIM + wv * 128 + s * 32;
                char* db = &xlds[wv][(s * 2 + (t >> 4)) * 1024 + (t & 15) * 16];
                #pragma unroll
                for (int g = 0; g < 4; ++g) {
                    const float4 f0 = LDF4(xr, g * 8);
                    const float4 f1 = LDF4(xr, g * 8 + 4);
                    *(short8*)(db + g * 256) = cvt8(f0, f1);
                }
            }
        }

        const int pr0 = (tA < nT)      ? (int)wls[wv][tb + tA]      : -1;
        const int pr1 = (tA + 16 < nT) ? (int)wls[wv][tb + tA + 16] : -1;

        f32x4 acc00 = {0.f, 0.f, 0.f, 0.f};
        f32x4 acc01 = {0.f, 0.f, 0.f, 0.f};
        f32x4 acc10 = {0.f, 0.f, 0.f, 0.f};
        f32x4 acc11 = {0.f, 0.f, 0.f, 0.f};
        const char* xw = (const char*)&xlds[wv][0] + lane * 16;

        if (tb == 0) {
            // ---- 4. W batch1 (steps 2-3) issued; flies under MFMAs ----
            __builtin_amdgcn_sched_barrier(0);   // keep issue AFTER x-stage
            float4 b1a0lo[2], b1a0hi[2], b1a1lo[2], b1a1hi[2];
            #pragma unroll
            for (int s = 0; s < 2; ++s) {
                b1a0lo[s] = LDF4(wpA0, (s + 2) * 32);
                b1a0hi[s] = LDF4(wpA0, (s + 2) * 32 + 4);
                b1a1lo[s] = LDF4(wpA1, (s + 2) * 32);
                b1a1hi[s] = LDF4(wpA1, (s + 2) * 32 + 4);
            }

            // ---- 5. MFMA: batch0 steps (counted waits), then batch1 ----
            #pragma unroll
            for (int s = 0; s < 2; ++s) {
                const short8 A0 = cvt8(b0a0lo[s], b0a0hi[s]);
                const short8 A1 = cvt8(b0a1lo[s], b0a1hi[s]);
                const short8 B0 = *(const short8*)(xw + s * 2048);
                acc00 = __builtin_amdgcn_mfma_f32_16x16x32_bf16(A0, B0, acc00, 0, 0, 0);
                acc10 = __builtin_amdgcn_mfma_f32_16x16x32_bf16(A1, B0, acc10, 0, 0, 0);
                if (h2) {
                    const short8 B1 = *(const short8*)(xw + s * 2048 + 1024);
                    acc01 = __builtin_amdgcn_mfma_f32_16x16x32_bf16(A0, B1, acc01, 0, 0, 0);
                    acc11 = __builtin_amdgcn_mfma_f32_16x16x32_bf16(A1, B1, acc11, 0, 0, 0);
                }
            }
            #pragma unroll
            for (int s = 0; s < 2; ++s) {
                const short8 A0 = cvt8(b1a0lo[s], b1a0hi[s]);
                const short8 A1 = cvt8(b1a1lo[s], b1a1hi[s]);
                const short8 B0 = *(const short8*)(xw + (s + 2) * 2048);
                acc00 = __builtin_amdgcn_mfma_f32_16x16x32_bf16(A0, B0, acc00, 0, 0, 0);
                acc10 = __builtin_amdgcn_mfma_f32_16x16x32_bf16(A1, B0, acc10, 0, 0, 0);
                if (h2) {
                    const short8 B1 = *(const short8*)(xw + (s + 2) * 2048 + 1024);
                    acc01 = __builtin_amdgcn_mfma_f32_16x16x32_bf16(A0, B1, acc01, 0, 0, 0);
                    acc11 = __builtin_amdgcn_mfma_f32_16x16x32_bf16(A1, B1, acc11, 0, 0, 0);
                }
            }
        } else {
            // rare T>32 path: reload W (stream again; simple + correct)
            #pragma unroll
            for (int s = 0; s < 4; ++s) {
                const short8 A0 = cvt8(LDF4(wpA0, s * 32), LDF4(wpA0, s * 32 + 4));
                const short8 A1 = cvt8(LDF4(wpA1, s * 32), LDF4(wpA1, s * 32 + 4));
                const short8 B0 = *(const short8*)(xw + s * 2048);
                acc00 = __builtin_amdgcn_mfma_f32_16x16x32_bf16(A0, B0, acc00, 0, 0, 0);
                acc10 = __builtin_amdgcn_mfma_f32_16x16x32_bf16(A1, B0, acc10, 0, 0, 0);
                if (h2) {
                    const short8 B1 = *(const short8*)(xw + s * 2048 + 1024);
                    acc01 = __builtin_amdgcn_mfma_f32_16x16x32_bf16(A0, B1, acc01, 0, 0, 0);
                    acc11 = __builtin_amdgcn_mfma_f32_16x16x32_bf16(A1, B1, acc11, 0, 0, 0);
                }
            }
        }

        // ---- 6. k-combine on dead x regions (b128, conflict-free) ----
        if (wv != 0) {
            char* rb = &xlds[wv][lane * 16];
            *(f32x4*)(rb + 0)    = acc00;
            *(f32x4*)(rb + 1024) = acc01;
            *(f32x4*)(rb + 2048) = acc10;
            *(f32x4*)(rb + 3072) = acc11;
        }
        __syncthreads();
        if (wv == 0) {
            #pragma unroll
            for (int rr = 1; rr < 4; ++rr) {
                const char* rb = &xlds[rr][lane * 16];
                acc00 = acc00 + *(const f32x4*)(rb + 0);
                acc01 = acc01 + *(const f32x4*)(rb + 1024);
                acc10 = acc10 + *(const f32x4*)(rb + 2048);
                acc11 = acc11 + *(const f32x4*)(rb + 3072);
            }
            if (pr0 >= 0) {
                float2 o;
                o.x = glu_act(acc00[0] + bv0.x, acc00[1] + bv0.y);
                o.y = glu_act(acc00[2] + bv0.z, acc00[3] + bv0.w);
                *(float2*)&out[(size_t)pr0 * HALF_C + (cb0 >> 1)] = o;
                o.x = glu_act(acc10[0] + bv1.x, acc10[1] + bv1.y);
                o.y = glu_act(acc10[2] + bv1.z, acc10[3] + bv1.w);
                *(float2*)&out[(size_t)pr0 * HALF_C + (cb1 >> 1)] = o;
            }
            if (pr1 >= 0) {
                float2 o;
                o.x = glu_act(acc01[0] + bv0.x, acc01[1] + bv0.y);
                o.y = glu_act(acc01[2] + bv0.z, acc01[3] + bv0.w);
                *(float2*)&out[(size_t)pr1 * HALF_C + (cb0 >> 1)] = o;
                o.x = glu_act(acc11[0] + bv1.x, acc11[1] + bv1.y);
                o.y = glu_act(acc11[2] + bv1.z, acc11[3] + bv1.w);
                *(float2*)&out[(size_t)pr1 * HALF_C + (cb1 >> 1)] = o;
            }
        }
    }
}

extern "C" void kernel_launch(void* const* d_in, const int* in_sizes, int n_in,
                              void* d_out, int out_size, void* d_ws, size_t ws_size,
                              hipStream_t stream) {
    const float* x    = (const float*)d_in[0];
    const int*   idx  = (const int*)d_in[1];
    const float* w    = (const float*)d_in[2];
    const float* bias = (const float*)d_in[3];
    float* out = (float*)d_out;

    dim3 grid(CDIM / 32, NEXP);   // (32, 32) = 1024 blocks = 4/CU
    moe_mlp1_kernel<<<grid, 256, 0, stream>>>(x, idx, w, bias, out);
}